// Round 5
// baseline (621.801 us; speedup 1.0000x reference)
//
#include <hip/hip_runtime.h>

// Problem constants (match reference file)
#define N_NODES 2000000
#define N_EDGES 32000000
#define N_OUT   400000   // N_NODES / 5
#define EPT     16       // edges per thread
#define NXCD    8        // MI355X: 8 XCDs

typedef int  iv4 __attribute__((ext_vector_type(4)));   // native vector for nontemporal builtin

// s_getreg_b32 immediate: ((size-1)<<11) | (offset<<6) | id ; HW_REG_XCC_ID = 20 (gfx940+)
#define GETREG_IMM(SZ, OFF, ID) ((((SZ) - 1) << 11) | ((OFF) << 6) | (ID))

// ---------------------------------------------------------------------------
// Replica-path scatter: atomics go to agg_r[xcd][d/5] with WORKGROUP scope.
// Global atomics without device scope execute at the issuing XCD's L2; all
// CUs of one XCD share that L2, and replica partitioning by *physical* XCC id
// guarantees no other XCD ever touches the same replica during this kernel.
// Dispatch-end release flushes L2 so the reduce kernel sees the values.
// ---------------------------------------------------------------------------
__global__ __launch_bounds__(256, 4) void gcn_edge_scatter_rep(
    const int* __restrict__ src,
    const int* __restrict__ dst,
    const float* __restrict__ x,
    float* __restrict__ agg_r)   // [NXCD][N_OUT]
{
    const int xcc = __builtin_amdgcn_s_getreg(GETREG_IMM(4, 0, 20)) & (NXCD - 1);
    float* my_agg = agg_r + (size_t)xcc * N_OUT;

    const long long base = ((long long)blockIdx.x * blockDim.x + threadIdx.x) * EPT;
    if (base >= N_EDGES) return;  // N_EDGES % EPT == 0: live thread => full batch

    iv4 d4[EPT / 4], s4[EPT / 4];
#pragma unroll
    for (int c = 0; c < EPT / 4; ++c)
        d4[c] = __builtin_nontemporal_load(reinterpret_cast<const iv4*>(dst + base) + c);
#pragma unroll
    for (int c = 0; c < EPT / 4; ++c)
        s4[c] = __builtin_nontemporal_load(reinterpret_cast<const iv4*>(src + base) + c);

    int dd[EPT];
    int idx[EPT];
    bool pass[EPT];
#pragma unroll
    for (int c = 0; c < EPT / 4; ++c) {
#pragma unroll
        for (int j = 0; j < 4; ++j) {
            const int d = d4[c][j];
            const int s = s4[c][j];
            const bool p = (d % 5 == 0);
            dd[c * 4 + j]   = d;
            pass[c * 4 + j] = p;
            idx[c * 4 + j]  = p ? s : 0;   // masked lanes -> x[0] (broadcast line)
        }
    }

    float v[EPT];
#pragma unroll
    for (int k = 0; k < EPT; ++k)
        v[k] = x[idx[k]];

#pragma unroll
    for (int k = 0; k < EPT; ++k)
        if (pass[k])
            __hip_atomic_fetch_add(&my_agg[dd[k] / 5], v[k],
                                   __ATOMIC_RELAXED, __HIP_MEMORY_SCOPE_WORKGROUP);
}

// Fallback (ws too small): single agg, device-scope atomics (R4 behavior).
__global__ __launch_bounds__(256, 4) void gcn_edge_scatter_dev(
    const int* __restrict__ src,
    const int* __restrict__ dst,
    const float* __restrict__ x,
    float* __restrict__ agg)
{
    const long long base = ((long long)blockIdx.x * blockDim.x + threadIdx.x) * EPT;
    if (base >= N_EDGES) return;

    iv4 d4[EPT / 4], s4[EPT / 4];
#pragma unroll
    for (int c = 0; c < EPT / 4; ++c)
        d4[c] = __builtin_nontemporal_load(reinterpret_cast<const iv4*>(dst + base) + c);
#pragma unroll
    for (int c = 0; c < EPT / 4; ++c)
        s4[c] = __builtin_nontemporal_load(reinterpret_cast<const iv4*>(src + base) + c);

    int dd[EPT]; int idx[EPT]; bool pass[EPT];
#pragma unroll
    for (int c = 0; c < EPT / 4; ++c) {
#pragma unroll
        for (int j = 0; j < 4; ++j) {
            const int d = d4[c][j];
            const int s = s4[c][j];
            const bool p = (d % 5 == 0);
            dd[c * 4 + j] = d; pass[c * 4 + j] = p; idx[c * 4 + j] = p ? s : 0;
        }
    }
    float v[EPT];
#pragma unroll
    for (int k = 0; k < EPT; ++k) v[k] = x[idx[k]];
#pragma unroll
    for (int k = 0; k < EPT; ++k)
        if (pass[k]) atomicAdd(&agg[dd[k] / 5], v[k]);
}

// ---------------------------------------------------------------------------
// Fused reduce(8 replicas) + epilogue.
// agg_node = (sum_r rep[r][i]) * w_conv + b_conv; t_j = relu(a*(w1[0,j]+w1[1,j])+b1[j]);
// out = sum_j t_j*w2[j] + b2.
// ---------------------------------------------------------------------------
__global__ __launch_bounds__(256) void gcn_reduce_epilogue(
    const float* __restrict__ agg_r,   // [n_rep][N_OUT]
    int n_rep,
    const float* __restrict__ w_conv,
    const float* __restrict__ b_conv,
    const float* __restrict__ w1,   // [2,4] row-major
    const float* __restrict__ b1,   // [4]
    const float* __restrict__ w2,   // [4,1]
    const float* __restrict__ b2,   // [1]
    float* __restrict__ out)
{
    const int i = blockIdx.x * blockDim.x + threadIdx.x;
    if (i >= N_OUT) return;
    float s = 0.0f;
    for (int r = 0; r < n_rep; ++r)
        s += agg_r[(size_t)r * N_OUT + i];
    const float a = s * w_conv[0] + b_conv[0];
    float rr = b2[0];
#pragma unroll
    for (int j = 0; j < 4; ++j) {
        float t = fmaf(a, w1[j] + w1[4 + j], b1[j]);
        t = fmaxf(t, 0.0f);
        rr = fmaf(t, w2[j], rr);
    }
    out[i] = rr;
}

extern "C" void kernel_launch(void* const* d_in, const int* in_sizes, int n_in,
                              void* d_out, int out_size, void* d_ws, size_t ws_size,
                              hipStream_t stream) {
    const float* x      = (const float*)d_in[0];
    const int*   ei     = (const int*)  d_in[1];  // [2, N_EDGES]: src row then dst row
    const float* w_conv = (const float*)d_in[2];
    const float* b_conv = (const float*)d_in[3];
    const float* w1     = (const float*)d_in[4];
    const float* b1     = (const float*)d_in[5];
    const float* w2     = (const float*)d_in[6];
    const float* b2     = (const float*)d_in[7];
    float* out = (float*)d_out;
    float* agg = (float*)d_ws;

    const size_t rep_bytes = (size_t)NXCD * N_OUT * sizeof(float);
    const bool use_rep = (ws_size >= rep_bytes);
    const int grid_scatter = (N_EDGES / EPT + 255) / 256;   // 7813

    if (use_rep) {
        (void)hipMemsetAsync(agg, 0, rep_bytes, stream);
        gcn_edge_scatter_rep<<<grid_scatter, 256, 0, stream>>>(ei, ei + N_EDGES, x, agg);
        gcn_reduce_epilogue<<<(N_OUT + 255) / 256, 256, 0, stream>>>(
            agg, NXCD, w_conv, b_conv, w1, b1, w2, b2, out);
    } else {
        (void)hipMemsetAsync(agg, 0, (size_t)N_OUT * sizeof(float), stream);
        gcn_edge_scatter_dev<<<grid_scatter, 256, 0, stream>>>(ei, ei + N_EDGES, x, agg);
        gcn_reduce_epilogue<<<(N_OUT + 255) / 256, 256, 0, stream>>>(
            agg, 1, w_conv, b_conv, w1, b1, w2, b2, out);
    }
}

// Round 6
// 457.443 us; speedup vs baseline: 1.3593x; 1.3593x over previous
//
#include <hip/hip_runtime.h>

// Problem constants (match reference file)
#define N_NODES 2000000
#define N_EDGES 32000000
#define N_OUT   400000          // N_NODES / 5
#define NBUCKET 256             // out-index buckets
#define BSZ     1568            // bucket width: 256*1568 = 401408 >= 400000; local fits 11 bits
#define CAP_BLK 64              // per-block per-bucket LDS staging capacity (u32)
#define CHUNK   32768           // edges per block, phase 1 (256 thr * 4 edges * 32 iters)
#define CAP_BKT 28672           // per-bucket payload capacity (lambda=25000, +23 sigma)
#define KSLICE  4               // phase-2 slices per bucket

typedef int iv4 __attribute__((ext_vector_type(4)));

// ---------------------------------------------------------------------------
// Phase 1: bin filtered edges into 256 buckets by out-index.
// payload u32 = (src << 11) | local, src < 2^21, local < 1568 < 2^11.
// LDS-staged per bucket; one global cursor atomic per (block,bucket) at flush.
// Rare staging overflow -> direct atomicAdd into the bucket's overflow row.
// ---------------------------------------------------------------------------
__global__ __launch_bounds__(256, 2) void p1_bin(
    const int* __restrict__ src,
    const int* __restrict__ dst,
    const float* __restrict__ x,
    unsigned* __restrict__ cnt,        // [NBUCKET]
    float* __restrict__ partials,      // [NBUCKET][KSLICE+1][BSZ]
    unsigned* __restrict__ payload)    // [NBUCKET][CAP_BKT]
{
    __shared__ unsigned s_cur[NBUCKET];
    __shared__ unsigned s_base[NBUCKET];
    __shared__ unsigned s_stage[NBUCKET][CAP_BLK];

    const int tid = threadIdx.x;
    if (tid < NBUCKET) s_cur[tid] = 0;
    __syncthreads();

    const long long blockStart = (long long)blockIdx.x * CHUNK;
    const int NIT = CHUNK / 1024;   // 32 iterations; 1024 edges per block-iter

    // software-pipelined streaming: prefetch next iter's int4 pair
    long long b0 = blockStart + (long long)tid * 4;
    bool valid0 = (b0 < N_EDGES);
    iv4 d4 = valid0 ? *reinterpret_cast<const iv4*>(dst + b0) : (iv4)0;
    iv4 s4 = valid0 ? *reinterpret_cast<const iv4*>(src + b0) : (iv4)0;

    for (int it = 0; it < NIT; ++it) {
        iv4 nd = (iv4)0, ns = (iv4)0;
        bool nvalid = false;
        if (it + 1 < NIT) {
            const long long bn = blockStart + (long long)(it + 1) * 1024 + tid * 4;
            nvalid = (bn < N_EDGES);
            if (nvalid) {
                nd = *reinterpret_cast<const iv4*>(dst + bn);
                ns = *reinterpret_cast<const iv4*>(src + bn);
            }
        }
        if (valid0) {
#pragma unroll
            for (int j = 0; j < 4; ++j) {
                const int d = d4[j];
                if (d % 5 == 0) {
                    const int g = d / 5;                 // 0..399999
                    const int b = g / BSZ;               // 0..255
                    const unsigned local = (unsigned)(g - b * BSZ);
                    const unsigned p = ((unsigned)s4[j] << 11) | local;
                    const unsigned slot = atomicAdd(&s_cur[b], 1u);
                    if (slot < CAP_BLK) {
                        s_stage[b][slot] = p;
                    } else {
                        // rare: direct device-scope add into overflow row
                        const float v = x[s4[j]];
                        atomicAdd(&partials[((size_t)b * (KSLICE + 1) + KSLICE) * BSZ + local], v);
                    }
                }
            }
        }
        d4 = nd; s4 = ns; valid0 = nvalid;
    }
    __syncthreads();

    // reserve payload runs: 256 parallel cursor atomics
    if (tid < NBUCKET) {
        const unsigned c = min(s_cur[tid], (unsigned)CAP_BLK);
        s_cur[tid] = c;
        s_base[tid] = atomicAdd(&cnt[tid], c);
    }
    __syncthreads();

    // flush: wave w handles buckets w, w+4, ... (CAP_BLK <= 64 lanes: one pass)
    const int wave = tid >> 6, lane = tid & 63;
    for (int b = wave; b < NBUCKET; b += 4) {
        const unsigned c = s_cur[b];
        if ((unsigned)lane < c)
            payload[(size_t)b * CAP_BKT + s_base[b] + lane] = s_stage[b][lane];
    }
}

// ---------------------------------------------------------------------------
// Phase 2: per (bucket, slice): accumulate payload into a 1568-float LDS
// accumulator via ds_add_f32, gathers batched 8-deep for MLP, then write the
// dense partial row.
// ---------------------------------------------------------------------------
__global__ __launch_bounds__(256) void p2_accum(
    const unsigned* __restrict__ cnt,
    const unsigned* __restrict__ payload,
    const float* __restrict__ x,
    float* __restrict__ partials)
{
    __shared__ float acc[BSZ];
    const int b = blockIdx.x >> 2;        // KSLICE = 4
    const int j = blockIdx.x & 3;
    const int tid = threadIdx.x;

    for (int i = tid; i < BSZ; i += 256) acc[i] = 0.0f;
    __syncthreads();

    unsigned n = cnt[b];
    if (n > CAP_BKT) n = CAP_BKT;         // safety clamp (never expected)
    const unsigned beg = (unsigned)(((unsigned long long)n * j) / KSLICE);
    const unsigned end = (unsigned)(((unsigned long long)n * (j + 1)) / KSLICE);
    const unsigned* pb = payload + (size_t)b * CAP_BKT;

    unsigned i0 = beg + tid;
    // 8-deep batches: payload reads, then gathers, then LDS adds
    for (; i0 + 7u * 256u < end; i0 += 8u * 256u) {
        unsigned pv[8]; float vv[8];
#pragma unroll
        for (int u = 0; u < 8; ++u) pv[u] = pb[i0 + u * 256u];
#pragma unroll
        for (int u = 0; u < 8; ++u) vv[u] = x[pv[u] >> 11];
#pragma unroll
        for (int u = 0; u < 8; ++u)
            __hip_atomic_fetch_add(&acc[pv[u] & 2047u], vv[u],
                                   __ATOMIC_RELAXED, __HIP_MEMORY_SCOPE_WORKGROUP);
    }
    for (; i0 < end; i0 += 256u) {
        const unsigned p = pb[i0];
        const float v = x[p >> 11];
        __hip_atomic_fetch_add(&acc[p & 2047u], v,
                               __ATOMIC_RELAXED, __HIP_MEMORY_SCOPE_WORKGROUP);
    }
    __syncthreads();

    float* row = partials + ((size_t)b * (KSLICE + 1) + j) * BSZ;
    for (int i = tid; i < BSZ; i += 256) row[i] = acc[i];
}

// ---------------------------------------------------------------------------
// Phase 3: sum KSLICE+1 partial rows, folded affine + 2->4->1 MLP, write out.
// ---------------------------------------------------------------------------
__global__ __launch_bounds__(256) void p3_out(
    const float* __restrict__ partials,
    const float* __restrict__ w_conv,
    const float* __restrict__ b_conv,
    const float* __restrict__ w1,   // [2,4] row-major
    const float* __restrict__ b1,
    const float* __restrict__ w2,
    const float* __restrict__ b2,
    float* __restrict__ out)
{
    const int i = blockIdx.x * 256 + threadIdx.x;
    if (i >= N_OUT) return;
    const int b = i / BSZ;
    const int local = i - b * BSZ;
    const float* pr = partials + (size_t)b * (KSLICE + 1) * BSZ + local;
    float s = 0.0f;
#pragma unroll
    for (int r = 0; r <= KSLICE; ++r) s += pr[(size_t)r * BSZ];
    const float a = s * w_conv[0] + b_conv[0];
    float rr = b2[0];
#pragma unroll
    for (int jj = 0; jj < 4; ++jj) {
        float t = fmaf(a, w1[jj] + w1[4 + jj], b1[jj]);
        rr = fmaf(fmaxf(t, 0.0f), w2[jj], rr);
    }
    out[i] = rr;
}

// ---------------------------------------------------------------------------
// Fallback (ws too small): R4-style direct device-atomic scatter + epilogue.
// ---------------------------------------------------------------------------
__global__ __launch_bounds__(256, 4) void gcn_edge_scatter_dev(
    const int* __restrict__ src,
    const int* __restrict__ dst,
    const float* __restrict__ x,
    float* __restrict__ agg)
{
    const long long base = ((long long)blockIdx.x * blockDim.x + threadIdx.x) * 16;
    if (base >= N_EDGES) return;
    iv4 d4[4], s4[4];
#pragma unroll
    for (int c = 0; c < 4; ++c)
        d4[c] = *(reinterpret_cast<const iv4*>(dst + base) + c);
#pragma unroll
    for (int c = 0; c < 4; ++c)
        s4[c] = *(reinterpret_cast<const iv4*>(src + base) + c);
    int dd[16]; int idx[16]; bool pass[16];
#pragma unroll
    for (int c = 0; c < 4; ++c)
#pragma unroll
        for (int j = 0; j < 4; ++j) {
            const int d = d4[c][j];
            const bool p = (d % 5 == 0);
            dd[c * 4 + j] = d; pass[c * 4 + j] = p;
            idx[c * 4 + j] = p ? s4[c][j] : 0;
        }
    float v[16];
#pragma unroll
    for (int k = 0; k < 16; ++k) v[k] = x[idx[k]];
#pragma unroll
    for (int k = 0; k < 16; ++k)
        if (pass[k]) atomicAdd(&agg[dd[k] / 5], v[k]);
}

__global__ __launch_bounds__(256) void gcn_epilogue_fb(
    const float* __restrict__ agg,
    const float* __restrict__ w_conv, const float* __restrict__ b_conv,
    const float* __restrict__ w1, const float* __restrict__ b1,
    const float* __restrict__ w2, const float* __restrict__ b2,
    float* __restrict__ out)
{
    const int i = blockIdx.x * 256 + threadIdx.x;
    if (i >= N_OUT) return;
    const float a = agg[i] * w_conv[0] + b_conv[0];
    float r = b2[0];
#pragma unroll
    for (int j = 0; j < 4; ++j) {
        float t = fmaf(a, w1[j] + w1[4 + j], b1[j]);
        r = fmaf(fmaxf(t, 0.0f), w2[j], r);
    }
    out[i] = r;
}

extern "C" void kernel_launch(void* const* d_in, const int* in_sizes, int n_in,
                              void* d_out, int out_size, void* d_ws, size_t ws_size,
                              hipStream_t stream) {
    const float* x      = (const float*)d_in[0];
    const int*   ei     = (const int*)  d_in[1];  // [2, N_EDGES]: src row then dst row
    const float* w_conv = (const float*)d_in[2];
    const float* b_conv = (const float*)d_in[3];
    const float* w1     = (const float*)d_in[4];
    const float* b1     = (const float*)d_in[5];
    const float* w2     = (const float*)d_in[6];
    const float* b2     = (const float*)d_in[7];
    float* out = (float*)d_out;

    // ws layout: [cnt 1KB][partials 8.03MB][payload 29.36MB]
    const size_t part_off   = 1024;
    const size_t part_bytes = (size_t)NBUCKET * (KSLICE + 1) * BSZ * sizeof(float);
    const size_t pay_off    = (part_off + part_bytes + 255) & ~(size_t)255;
    const size_t pay_bytes  = (size_t)NBUCKET * CAP_BKT * sizeof(unsigned);
    const size_t need       = pay_off + pay_bytes;

    if (ws_size >= need) {
        unsigned* cnt      = (unsigned*)d_ws;
        float*    partials = (float*)((char*)d_ws + part_off);
        unsigned* payload  = (unsigned*)((char*)d_ws + pay_off);

        (void)hipMemsetAsync(d_ws, 0, pay_off, stream);   // zero cnt + partials

        const int grid_p1 = (int)((N_EDGES + CHUNK - 1) / CHUNK);  // 977
        p1_bin<<<grid_p1, 256, 0, stream>>>(ei, ei + N_EDGES, x, cnt, partials, payload);
        p2_accum<<<NBUCKET * KSLICE, 256, 0, stream>>>(cnt, payload, x, partials);
        p3_out<<<(N_OUT + 255) / 256, 256, 0, stream>>>(
            partials, w_conv, b_conv, w1, b1, w2, b2, out);
    } else {
        float* agg = (float*)d_ws;
        (void)hipMemsetAsync(agg, 0, (size_t)N_OUT * sizeof(float), stream);
        gcn_edge_scatter_dev<<<(N_EDGES / 16 + 255) / 256, 256, 0, stream>>>(
            ei, ei + N_EDGES, x, agg);
        gcn_epilogue_fb<<<(N_OUT + 255) / 256, 256, 0, stream>>>(
            agg, w_conv, b_conv, w1, b1, w2, b2, out);
    }
}